// Round 12
// baseline (153.179 us; speedup 1.0000x reference)
//
#include <hip/hip_runtime.h>
#include <hip/hip_bf16.h>
#include <math.h>

typedef __bf16 bf16_t;
typedef __bf16 bf16x8 __attribute__((ext_vector_type(8)));
typedef float f32x4 __attribute__((ext_vector_type(4)));
typedef float f32x16 __attribute__((ext_vector_type(16)));
typedef unsigned u32x2 __attribute__((ext_vector_type(2)));

#define NPOS 4096
#define LOG2E 1.4426950408889634f

__device__ __forceinline__ f32x4 mfma16(bf16x8 a, bf16x8 b, f32x4 c) {
    return __builtin_amdgcn_mfma_f32_16x16x32_bf16(a, b, c, 0, 0, 0);
}
__device__ __forceinline__ f32x16 mfma32(bf16x8 a, bf16x8 b, f32x16 c) {
    return __builtin_amdgcn_mfma_f32_32x32x16_bf16(a, b, c, 0, 0, 0);
}

typedef __attribute__((address_space(1))) const unsigned gas_u32;
typedef __attribute__((address_space(3))) unsigned las_u32;
__device__ __forceinline__ void gl_lds16(const char* g, char* l) {
    __builtin_amdgcn_global_load_lds((gas_u32*)g, (las_u32*)l, 16, 0, 0);
}

// raw v_exp_f32 (2^x)
__device__ __forceinline__ float fexp2(float x) {
    float r; asm("v_exp_f32 %0, %1" : "=v"(r) : "v"(x)); return r;
}

// counted-vmcnt barrier (T4)
#define BARC(N) do {                                                          \
    asm volatile("s_waitcnt vmcnt(" #N ") lgkmcnt(0)" ::: "memory");          \
    __builtin_amdgcn_sched_barrier(0);                                        \
    __builtin_amdgcn_s_barrier();                                             \
    __builtin_amdgcn_sched_barrier(0);                                        \
} while (0)

__device__ __forceinline__ char* sel3(char* a, char* b, char* c, int i) {
    return i == 0 ? a : (i == 1 ? b : c);
}

// ---- LDS tile layout (0-conflict, verified r4/r8/r9): 256B rows, byte ^= (row&15)<<4 ----
template<int BYTES>
__device__ __forceinline__ void stG(char* lds, const char* g, int w, int lane) {
    constexpr int NC = BYTES / 4096;
#pragma unroll
    for (int c = 0; c < NC; ++c) {
        int j = (w * NC + c) * 1024 + lane * 16;
        gl_lds16(g + (j ^ (((j >> 8) & 15) << 4)), lds + j);
    }
}
// 64-key V tile for D=64 (stream B): LDS row = 2 d-rows, col=(d&1)*128 + key*2
template<int BYTES>
__device__ __forceinline__ void stV(char* lds, const char* g, int w, int lane) {
    constexpr int NC = BYTES / 4096;
#pragma unroll
    for (int c = 0; c < NC; ++c) {
        int j = (w * NC + c) * 1024 + lane * 16;
        int row = j >> 8;
        int col = (j & 255) ^ ((row & 15) << 4);
        int d = (row << 1) | (col >> 7);
        gl_lds16(g + (size_t)d * (NPOS * 2) + (col & 127), lds + j);
    }
}
// 32-key V tile for D=128 (stream A): LDS row = 4 d-rows, col=(d&3)*64 + key*2
template<int BYTES>
__device__ __forceinline__ void stV32(char* lds, const char* g, int w, int lane) {
    constexpr int NC = BYTES / 4096;
#pragma unroll
    for (int c = 0; c < NC; ++c) {
        int j = (w * NC + c) * 1024 + lane * 16;
        int row = j >> 8;
        int col = (j & 255) ^ ((row & 15) << 4);
        int d = (row << 2) | (col >> 6);
        gl_lds16(g + (size_t)d * (NPOS * 2) + (col & 63), lds + j);
    }
}

template<int D>
__device__ __forceinline__ bf16x8 ldK(const char* lds, int key, int dbyte) {
    if constexpr (D == 128) {
        return *(const bf16x8*)(lds + key * 256 + (dbyte ^ ((key & 15) << 4)));
    } else {
        int row = key >> 1;
        int col = ((key & 1) << 7) | dbyte;
        return *(const bf16x8*)(lds + row * 256 + (col ^ ((row & 15) << 4)));
    }
}
__device__ __forceinline__ bf16x8 ldV(const char* lds, int d, int kbyte) {
    int row = d >> 1;
    int col = ((d & 1) << 7) | kbyte;
    return *(const bf16x8*)(lds + row * 256 + (col ^ ((row & 15) << 4)));
}
__device__ __forceinline__ bf16x8 ldV32(const char* lds, int d, int kbyte) {
    int row = d >> 2;
    int col = ((d & 3) << 6) | kbyte;
    return *(const bf16x8*)(lds + row * 256 + (col ^ ((row & 15) << 4)));
}

// inline fp32 -> bf16 weight fragment (weights are L1/L2-hot, tiny)
__device__ __forceinline__ bf16x8 ldw(const float* w) {
    float4 a = *(const float4*)w, b = *(const float4*)(w + 4);
    bf16x8 r;
    r[0] = (bf16_t)a.x; r[1] = (bf16_t)a.y; r[2] = (bf16_t)a.z; r[3] = (bf16_t)a.w;
    r[4] = (bf16_t)b.x; r[5] = (bf16_t)b.y; r[6] = (bf16_t)b.z; r[7] = (bf16_t)b.w;
    return r;
}

__device__ __forceinline__ unsigned pkbf(float a, float b) {
    union { bf16_t h[2]; unsigned u; } t;
    t.h[0] = (bf16_t)a; t.h[1] = (bf16_t)b;
    return t.u;
}
#define MKPA(sb, base) ({                                                   \
    unsigned a0_ = pkbf((sb)[(base)+0], (sb)[(base)+1]);                    \
    unsigned a1_ = pkbf((sb)[(base)+2], (sb)[(base)+3]);                    \
    unsigned a2_ = pkbf((sb)[(base)+4], (sb)[(base)+5]);                    \
    unsigned a3_ = pkbf((sb)[(base)+6], (sb)[(base)+7]);                    \
    u32x2 r0_ = __builtin_amdgcn_permlane32_swap(a2_, a0_, false, false);   \
    u32x2 r1_ = __builtin_amdgcn_permlane32_swap(a3_, a1_, false, false);   \
    union { unsigned u[4]; bf16x8 v; } pu_;                                 \
    pu_.u[0] = r0_.y; pu_.u[1] = r1_.y; pu_.u[2] = r0_.x; pu_.u[3] = r1_.x; \
    pu_.v; })

// ================= fused producer: transpose+convert+3 projections =================
// F: [B][K][N] fp32 features. Stages bf16 X-tile [64n][K] in LDS via the proven
// 64x65 fp32 transpose buffer, then computes Q (scaled, [N][MQ]), K ([N][MK]),
// V ([MV][N]) with inline fp32->bf16 weight conversion.
template<int K, int MQ, int MK, int MV>
__device__ void prod_body(const float* __restrict__ F,
                          const float* __restrict__ wq, const float* __restrict__ bq, float sq,
                          const float* __restrict__ wk, const float* __restrict__ bk,
                          const float* __restrict__ wv, const float* __restrict__ bv,
                          bf16_t* __restrict__ Qo, bf16_t* __restrict__ Ko, bf16_t* __restrict__ Vo,
                          char* smem, int bid, int tid)
{
    constexpr int RB = K * 2;
    int b = bid >> 6, n0 = (bid & 63) << 6;
    int wave = tid >> 6, lane = tid & 63, g = lane >> 4, lr = lane & 15;

    // ---- inline transpose: F[b][c][n0..n0+63] -> swizzled bf16 tile [64][K] ----
    float (*tile)[65] = (float(*)[65])(smem + 64 * RB);
    const float* fb = F + (size_t)b * K * NPOS;
    for (int c0 = 0; c0 < K; c0 += 64) {
        const float* sp = fb + (size_t)c0 * NPOS + n0;
        __syncthreads();
#pragma unroll
        for (int i = 0; i < 16; i++) {
            int idx = tid + i * 256; int c = idx >> 6, n = idx & 63;
            tile[c][n] = sp[(size_t)c * NPOS + n];
        }
        __syncthreads();
#pragma unroll
        for (int i = 0; i < 16; i++) {
            int idx = tid + i * 256; int n = idx >> 6, c = idx & 63;
            int colb = (c0 + c) * 2;
            *(bf16_t*)(smem + n * RB + (colb ^ ((n & 7) << 4))) = (bf16_t)tile[c][n];
        }
    }
    __syncthreads();

    f32x4 aq[MQ / 16], ak[MK / 16], av[MV / 16];
#pragma unroll
    for (int ob = 0; ob < MQ / 16; ++ob) aq[ob] = f32x4{0.f,0.f,0.f,0.f};
#pragma unroll
    for (int ob = 0; ob < MK / 16; ++ob) ak[ob] = f32x4{0.f,0.f,0.f,0.f};
#pragma unroll
    for (int ob = 0; ob < MV / 16; ++ob) av[ob] = f32x4{0.f,0.f,0.f,0.f};
    int xrow = wave * 16 + lr;
#pragma unroll
    for (int ks = 0; ks < K / 32; ++ks) {
        bf16x8 xf = *(const bf16x8*)(smem + xrow * RB + ((((ks * 32 + g * 8) * 2)) ^ ((xrow & 7) << 4)));
#pragma unroll
        for (int ob = 0; ob < MQ / 16; ++ob)
            aq[ob] = mfma16(xf, ldw(wq + (size_t)(ob * 16 + lr) * K + ks * 32 + g * 8), aq[ob]);
#pragma unroll
        for (int ob = 0; ob < MK / 16; ++ob)
            ak[ob] = mfma16(xf, ldw(wk + (size_t)(ob * 16 + lr) * K + ks * 32 + g * 8), ak[ob]);
#pragma unroll
        for (int ob = 0; ob < MV / 16; ++ob)
            av[ob] = mfma16(ldw(wv + (size_t)(ob * 16 + lr) * K + ks * 32 + g * 8), xf, av[ob]);
    }
#pragma unroll
    for (int ob = 0; ob < MQ / 16; ++ob) {
        int o = ob * 16 + lr;
        float bs = bq[o];
#pragma unroll
        for (int r = 0; r < 4; r++) {
            size_t n = (size_t)b * NPOS + n0 + wave * 16 + g * 4 + r;
            Qo[n * MQ + o] = (bf16_t)((aq[ob][r] + bs) * sq);
        }
    }
#pragma unroll
    for (int ob = 0; ob < MK / 16; ++ob) {
        int o = ob * 16 + lr;
        float bs = bk[o];
#pragma unroll
        for (int r = 0; r < 4; r++) {
            size_t n = (size_t)b * NPOS + n0 + wave * 16 + g * 4 + r;
            Ko[n * MK + o] = (bf16_t)(ak[ob][r] + bs);
        }
    }
#pragma unroll
    for (int ob = 0; ob < MV / 16; ++ob) {
#pragma unroll
        for (int r = 0; r < 4; r++) {
            int o = ob * 16 + g * 4 + r;
            size_t idx = ((size_t)b * MV + o) * NPOS + n0 + wave * 16 + lr;
            Vo[idx] = (bf16_t)(av[ob][r] + bv[o]);
        }
    }
}

__global__ __launch_bounds__(256, 2) void k_prodf(const float* f2d, const float* f3d,
                                                  const float* wqA, const float* bqA,
                                                  const float* wkA, const float* bkA,
                                                  const float* wvA, const float* bvA,
                                                  const float* wqB, const float* bqB,
                                                  const float* wkB, const float* bkB,
                                                  const float* wvB, const float* bvB,
                                                  bf16_t* QtA, bf16_t* KtA_, bf16_t* VA_,
                                                  bf16_t* QtB, bf16_t* KtB_, bf16_t* VB_)
{
    extern __shared__ char smem[];
    const float sA = 0.08838834764831845f * LOG2E;
    const float sB = 0.125f * LOG2E;
    if (blockIdx.x < 256)
        prod_body<256, 128, 64, 64>(f2d, wqA, bqA, sA, wkB, bkB, wvB, bvB,
                                    QtA, KtB_, VB_, smem, blockIdx.x, threadIdx.x);
    else
        prod_body<128, 64, 128, 128>(f3d, wqB, bqB, sB, wkA, bkA, wvA, bvA,
                                     QtB, KtA_, VA_, smem, blockIdx.x - 256, threadIdx.x);
}

// ============ fused output projection: 2-way l-merge + GEMM + bias + residual ============
template<int K, int M>
__device__ void out_body(const bf16_t* __restrict__ Xt,
                         const float* __restrict__ lp,
                         const float* __restrict__ W,
                         const float* __restrict__ bias,
                         const float* __restrict__ resid,
                         float* __restrict__ outp,
                         char* smem, int bid, int tid)
{
    constexpr int RB = K * 2;
    int b = bid >> 6, n0 = (bid & 63) << 6;
    int wave = tid >> 6, lane = tid & 63, g = lane >> 4, lr = lane & 15;

#pragma unroll
    for (int j0 = 0; j0 < 64 * RB; j0 += 4096) {
        int j = j0 + tid * 16;
        int row = j / RB;
        int colb = j & (RB - 1);
        size_t n = (size_t)b * NPOS + n0 + row;
        float l1 = lp[n], l2 = lp[16384 + n];
        float inv = 1.f / (l1 + l2);
        float w1 = l1 * inv, w2 = l2 * inv;
        bf16x8 o1 = *(const bf16x8*)(Xt + n * K + (colb >> 1));
        bf16x8 o2 = *(const bf16x8*)(Xt + (size_t)16384 * K + n * K + (colb >> 1));
        bf16x8 xv;
#pragma unroll
        for (int e = 0; e < 8; ++e) xv[e] = (bf16_t)(w1 * (float)o1[e] + w2 * (float)o2[e]);
        *(bf16x8*)(smem + row * RB + (colb ^ ((row & 7) << 4))) = xv;
    }
    __syncthreads();

    f32x4 acc[M / 16];
#pragma unroll
    for (int ob = 0; ob < M / 16; ++ob) acc[ob] = f32x4{0.f,0.f,0.f,0.f};
    int xrow = wave * 16 + lr;
#pragma unroll
    for (int ks = 0; ks < K / 32; ++ks) {
        bf16x8 xf = *(const bf16x8*)(smem + xrow * RB + ((((ks * 32 + g * 8) * 2)) ^ ((xrow & 7) << 4)));
#pragma unroll
        for (int ob = 0; ob < M / 16; ++ob)
            acc[ob] = mfma16(ldw(W + (size_t)(ob * 16 + lr) * K + ks * 32 + g * 8), xf, acc[ob]);
    }
#pragma unroll
    for (int ob = 0; ob < M / 16; ++ob) {
#pragma unroll
        for (int r = 0; r < 4; r++) {
            int o = ob * 16 + g * 4 + r;
            size_t idx = ((size_t)b * M + o) * NPOS + n0 + wave * 16 + lr;
            outp[idx] = acc[ob][r] + bias[o] + resid[idx];
        }
    }
}

__global__ __launch_bounds__(256, 2) void k_outf(const bf16_t* OtHA, const float* lHA,
                                                 const bf16_t* OtHB, const float* lHB,
                                                 const float* wpA, const float* bpA, const float* f2d,
                                                 const float* wpB, const float* bpB, const float* f3d,
                                                 float* out)
{
    extern __shared__ char smem[];
    if (blockIdx.x < 256)
        out_body<128, 256>(OtHA, lHA, wpA, bpA, f2d, out, smem, blockIdx.x, threadIdx.x);
    else
        out_body<64, 128>(OtHB, lHB, wpB, bpB, f3d, out + 4194304, smem, blockIdx.x - 256, threadIdx.x);
}

// ======== attention A: D=128, KVBLK=32, K/V triple-buffered, software-pipelined (r11) ========
__device__ void attnA11(const bf16_t* __restrict__ Qt, const bf16_t* __restrict__ Kt,
                        const bf16_t* __restrict__ V, bf16_t* __restrict__ OtH,
                        float* __restrict__ lH, int b, int qblk, int half,
                        char* smem, int tid)
{
    char* Kb0 = smem;          char* Kb1 = smem + 8192;  char* Kb2 = smem + 16384;
    char* Vb0 = smem + 24576;  char* Vb1 = smem + 32768; char* Vb2 = smem + 40960;
    int w = tid >> 6, lane = tid & 63;
    int qcol = lane & 31, hi = lane >> 5;
    int q0 = qblk * 128 + w * 32;

    bf16x8 qf[8];
    const bf16_t* qp = Qt + ((size_t)b * NPOS + q0 + qcol) * 128 + hi * 8;
#pragma unroll
    for (int ks = 0; ks < 8; ++ks) qf[ks] = *(const bf16x8*)(qp + ks * 16);

    f32x16 acc[4];
#pragma unroll
    for (int cb = 0; cb < 4; ++cb)
#pragma unroll
        for (int i = 0; i < 16; ++i) acc[cb][i] = 0.f;
    float l_c = 0.f;

    const char* kg = (const char*)(Kt + (size_t)b * NPOS * 128) + (size_t)half * 64 * 8192;
    const char* vg = (const char*)(V + (size_t)b * 128 * NPOS) + (size_t)half * 4096;

    stG<8192>(Kb0, kg, w, lane);
    stV32<8192>(Vb0, vg, w, lane);
    stG<8192>(Kb1, kg + 8192, w, lane);
    stV32<8192>(Vb1, vg + 64, w, lane);
    BARC(4);

    f32x16 sE, sO;
#pragma unroll
    for (int i = 0; i < 16; ++i) sE[i] = 0.f;
#pragma unroll
    for (int ks = 0; ks < 8; ++ks)
        sE = mfma32(ldK<128>(Kb0, qcol, ks * 32 + hi * 16), qf[ks], sE);
    stG<8192>(Kb2, kg + 16384, w, lane);
    BARC(2);

    int ce = 0;
#pragma unroll 1
    for (int t2 = 0; t2 < 32; ++t2) {
        int t = 2 * t2;
        int c1 = ce + 1; if (c1 > 2) c1 -= 3;
        int c2 = ce + 2; if (c2 > 2) c2 -= 3;
        {
            int tK = t + 3; if (tK > 63) tK = 63;
            int tV = t + 2; if (tV > 63) tV = 63;
            stG<8192>(sel3(Kb0, Kb1, Kb2, ce), kg + (size_t)tK * 8192, w, lane);
            stV32<8192>(sel3(Vb0, Vb1, Vb2, c2), vg + (size_t)tV * 64, w, lane);
            const char* Kn = sel3(Kb0, Kb1, Kb2, c1);
#pragma unroll
            for (int i = 0; i < 16; ++i) sO[i] = 0.f;
            __builtin_amdgcn_s_setprio(1);
#pragma unroll
            for (int ks = 0; ks < 8; ++ks)
                sO = mfma32(ldK<128>(Kn, qcol, ks * 32 + hi * 16), qf[ks], sO);
            __builtin_amdgcn_s_setprio(0);
            float ps = 0.f;
#pragma unroll
            for (int i = 0; i < 16; ++i) { float e = fexp2(sE[i]); sE[i] = e; ps += e; }
            ps += __shfl_xor(ps, 32);
            l_c += ps;
            bf16x8 pa0 = MKPA(sE, 0), pa1 = MKPA(sE, 8);
            const char* Vc = sel3(Vb0, Vb1, Vb2, ce);
            __builtin_amdgcn_s_setprio(1);
#pragma unroll
            for (int cb = 0; cb < 4; ++cb) {
                int d = cb * 32 + qcol;
                acc[cb] = mfma32(pa0, ldV32(Vc, d, hi * 16), acc[cb]);
                acc[cb] = mfma32(pa1, ldV32(Vc, d, 32 + hi * 16), acc[cb]);
            }
            __builtin_amdgcn_s_setprio(0);
            BARC(4);
        }
        {
            int tK = t + 4; if (tK > 63) tK = 63;
            int tV = t + 3; if (tV > 63) tV = 63;
            stG<8192>(sel3(Kb0, Kb1, Kb2, c1), kg + (size_t)tK * 8192, w, lane);
            stV32<8192>(sel3(Vb0, Vb1, Vb2, ce), vg + (size_t)tV * 64, w, lane);
            const char* Kn = sel3(Kb0, Kb1, Kb2, c2);
#pragma unroll
            for (int i = 0; i < 16; ++i) sE[i] = 0.f;
            __builtin_amdgcn_s_setprio(1);
#pragma unroll
            for (int ks = 0; ks < 8; ++ks)
                sE = mfma32(ldK<128>(Kn, qcol, ks * 32 + hi * 16), qf[ks], sE);
            __builtin_amdgcn_s_setprio(0);
            float ps = 0.f;
#pragma unroll
            for (int i = 0; i < 16; ++i) { float e = fexp2(sO[i]); sO[i] = e; ps += e; }
            ps += __shfl_xor(ps, 32);
            l_c += ps;
            bf16x8 pa0 = MKPA(sO, 0), pa1 = MKPA(sO, 8);
            const char* Vc = sel3(Vb0, Vb1, Vb2, c1);
            __builtin_amdgcn_s_setprio(1);
#pragma unroll
            for (int cb = 0; cb < 4; ++cb) {
                int d = cb * 32 + qcol;
                acc[cb] = mfma32(pa0, ldV32(Vc, d, hi * 16), acc[cb]);
                acc[cb] = mfma32(pa1, ldV32(Vc, d, 32 + hi * 16), acc[cb]);
            }
            __builtin_amdgcn_s_setprio(0);
            BARC(4);
        }
        ce = c2;
    }

    float linv = 1.f / l_c;
    size_t obase = (size_t)(half * 4 + b) * NPOS;
#pragma unroll
    for (int r = 0; r < 16; ++r) {
        int crow = (r & 3) + 8 * (r >> 2) + 4 * hi;
        float lr = __shfl(linv, crow);
        size_t nrow = obase + q0 + crow;
#pragma unroll
        for (int cb = 0; cb < 4; ++cb)
            OtH[nrow * 128 + cb * 32 + qcol] = (bf16_t)(acc[cb][r] * lr);
    }
    if (lane < 32) lH[obase + q0 + lane] = l_c;
}

// ======== attention B: D=64, KVBLK=64, K/V triple-buffered, software-pipelined (r11) ========
__device__ void attnB11(const bf16_t* __restrict__ Qt, const bf16_t* __restrict__ Kt,
                        const bf16_t* __restrict__ V, bf16_t* __restrict__ OtH,
                        float* __restrict__ lH, int b, int qblk, int half,
                        char* smem, int tid)
{
    char* Kb0 = smem;          char* Kb1 = smem + 8192;  char* Kb2 = smem + 16384;
    char* Vb0 = smem + 24576;  char* Vb1 = smem + 32768; char* Vb2 = smem + 40960;
    int w = tid >> 6, lane = tid & 63;
    int qcol = lane & 31, hi = lane >> 5;
    int q0 = qblk * 128 + w * 32;

    bf16x8 qf[4];
    const bf16_t* qp = Qt + ((size_t)b * NPOS + q0 + qcol) * 64 + hi * 8;
#pragma unroll
    for (int ks = 0; ks < 4; ++ks) qf[ks] = *(const bf16x8*)(qp + ks * 16);

    f32x16 acc[2];
#pragma unroll
    for (int cb = 0; cb < 2; ++cb)
#pragma unroll
        for (int i = 0; i < 16; ++i) acc[cb][i] = 0.f;
    float l_c = 0.f;

    const char* kg = (const char*)(Kt + (size_t)b * NPOS * 64) + (size_t)half * 32 * 8192;
    const char* vg = (const char*)(V + (size_t)b * 64 * NPOS) + (size_t)half * 4096;

    stG<8192>(Kb0, kg, w, lane);
    stV<8192>(Vb0, vg, w, lane);
    stG<8192>(Kb1, kg + 8192, w, lane);
    stV<8192>(Vb1, vg + 128, w, lane);
    BARC(4);

    f32x16 sE0, sE1, sO0, sO1;
#pragma unroll
    for (int i = 0; i < 16; ++i) { sE0[i] = 0.f; sE1[i] = 0.f; }
#pragma unroll
    for (int ks = 0; ks < 4; ++ks) {
        int dbyte = ks * 32 + hi * 16;
        sE0 = mfma32(ldK<64>(Kb0, qcol, dbyte), qf[ks], sE0);
        sE1 = mfma32(ldK<64>(Kb0, 32 + qcol, dbyte), qf[ks], sE1);
    }
    stG<8192>(Kb2, kg + 16384, w, lane);
    BARC(2);

    int ce = 0;
#pragma unroll 1
    for (int t2 = 0; t2 < 16; ++t2) {
        int t = 2 * t2;
        int c1 = ce + 1; if (c1 > 2) c1 -= 3;
        int c2 = ce + 2; if (c2 > 2) c2 -= 3;
        {
            int tK = t + 3; if (tK > 31) tK = 31;
            int tV = t + 2; if (tV > 31) tV = 31;
            stG<8192>(sel3(Kb0, Kb1, Kb2, ce), kg + (size_t)tK * 8192, w, lane);
            stV<8192>(sel3(Vb0, Vb1, Vb2, c2), vg + (size_t)tV * 128, w, lane);
            const char* Kn = sel3(Kb0, Kb1, Kb2, c1);
#pragma unroll
            for (int i = 0; i < 16; ++i) { sO0[i] = 0.f; sO1[i] = 0.f; }
            __builtin_amdgcn_s_setprio(1);
#pragma unroll
            for (int ks = 0; ks < 4; ++ks) {
                int dbyte = ks * 32 + hi * 16;
                sO0 = mfma32(ldK<64>(Kn, qcol, dbyte), qf[ks], sO0);
                sO1 = mfma32(ldK<64>(Kn, 32 + qcol, dbyte), qf[ks], sO1);
            }
            __builtin_amdgcn_s_setprio(0);
            float ps = 0.f;
#pragma unroll
            for (int i = 0; i < 16; ++i) { float e = fexp2(sE0[i]); sE0[i] = e; ps += e; }
#pragma unroll
            for (int i = 0; i < 16; ++i) { float e = fexp2(sE1[i]); sE1[i] = e; ps += e; }
            ps += __shfl_xor(ps, 32);
            l_c += ps;
            bf16x8 pa0 = MKPA(sE0, 0), pa1 = MKPA(sE0, 8);
            bf16x8 pa2 = MKPA(sE1, 0), pa3 = MKPA(sE1, 8);
            const char* Vc = sel3(Vb0, Vb1, Vb2, ce);
            __builtin_amdgcn_s_setprio(1);
#pragma unroll
            for (int cb = 0; cb < 2; ++cb) {
                int d = cb * 32 + qcol;
                acc[cb] = mfma32(pa0, ldV(Vc, d, 0  + hi * 16), acc[cb]);
                acc[cb] = mfma32(pa1, ldV(Vc, d, 32 + hi * 16), acc[cb]);
                acc[cb] = mfma32(pa2, ldV(Vc, d, 64 + hi * 16), acc[cb]);
                acc[cb] = mfma32(pa3, ldV(Vc, d, 96 + hi * 16), acc[cb]);
            }
            __builtin_amdgcn_s_setprio(0);
            BARC(4);
        }
        {
            int tK = t + 4; if (tK > 31) tK = 31;
            int tV = t + 3; if (tV > 31) tV = 31;
            stG<8192>(sel3(Kb0, Kb1, Kb2, c1), kg + (size_t)tK * 8192, w, lane);
            stV<8192>(sel3(Vb0, Vb1, Vb2, ce), vg + (size_t)tV * 128, w, lane);
            const char* Kn = sel3(Kb0, Kb1, Kb2, c2);
#pragma unroll
            for (int i = 0; i < 16; ++i) { sE0[i] = 0.f; sE1[i] = 0.f; }
            __builtin_amdgcn_s_setprio(1);
#pragma unroll
            for (int ks = 0; ks < 4; ++ks) {
                int dbyte = ks * 32 + hi * 16;
                sE0 = mfma32(ldK<64>(Kn, qcol, dbyte), qf[ks], sE0);
                sE1 = mfma32(ldK<64>(Kn, 32 + qcol, dbyte), qf[ks], sE1);
            }
            __builtin_amdgcn_s_setprio(0);
            float ps = 0.f;
#pragma unroll
            for (int i = 0; i < 16; ++i) { float e = fexp2(sO0[i]); sO0[i] = e; ps += e; }
#pragma unroll
            for (int i = 0; i < 16; ++i) { float e = fexp2(sO1[i]); sO1[i] = e; ps += e; }
            ps += __shfl_xor(ps, 32);
            l_c += ps;
            bf16x8 pa0 = MKPA(sO0, 0), pa1 = MKPA(sO0, 8);
            bf16x8 pa2 = MKPA(sO1, 0), pa3 = MKPA(sO1, 8);
            const char* Vc = sel3(Vb0, Vb1, Vb2, c1);
            __builtin_amdgcn_s_setprio(1);
#pragma unroll
            for (int cb = 0; cb < 2; ++cb) {
                int d = cb * 32 + qcol;
                acc[cb] = mfma32(pa0, ldV(Vc, d, 0  + hi * 16), acc[cb]);
                acc[cb] = mfma32(pa1, ldV(Vc, d, 32 + hi * 16), acc[cb]);
                acc[cb] = mfma32(pa2, ldV(Vc, d, 64 + hi * 16), acc[cb]);
                acc[cb] = mfma32(pa3, ldV(Vc, d, 96 + hi * 16), acc[cb]);
            }
            __builtin_amdgcn_s_setprio(0);
            BARC(4);
        }
        ce = c2;
    }

    float linv = 1.f / l_c;
    size_t obase = (size_t)(half * 4 + b) * NPOS;
#pragma unroll
    for (int r = 0; r < 16; ++r) {
        int crow = (r & 3) + 8 * (r >> 2) + 4 * hi;
        float lr = __shfl(linv, crow);
        size_t nrow = obase + q0 + crow;
#pragma unroll
        for (int cb = 0; cb < 2; ++cb)
            OtH[nrow * 64 + cb * 32 + qcol] = (bf16_t)(acc[cb][r] * lr);
    }
    if (lane < 32) lH[obase + q0 + lane] = l_c;
}

__global__ __launch_bounds__(256, 2) void k_attn11(const bf16_t* QtA, const bf16_t* KtA, const bf16_t* VA,
                                                   bf16_t* OtHA, float* lHA,
                                                   const bf16_t* QtB, const bf16_t* KtB, const bf16_t* VB,
                                                   bf16_t* OtHB, float* lHB)
{
    extern __shared__ char smem[];
    int bid = blockIdx.x, tid = threadIdx.x;
    if (bid < 256) {
        int x = bid & 7;   // XCD = (b<<1)|half keeps K/V half in its L2
        attnA11(QtA, KtA, VA, OtHA, lHA, x >> 1, bid >> 3, x & 1, smem, tid);
    } else {
        int u = bid - 256;
        int x = u & 7;
        attnB11(QtB, KtB, VB, OtHB, lHB, x >> 1, u >> 3, x & 1, smem, tid);
    }
}

extern "C" void kernel_launch(void* const* d_in, const int* in_sizes, int n_in,
                              void* d_out, int out_size, void* d_ws, size_t ws_size,
                              hipStream_t stream)
{
    (void)in_sizes; (void)n_in; (void)out_size; (void)ws_size;
    const float* f2d = (const float*)d_in[0];
    const float* f3d = (const float*)d_in[1];
    const float* wqA = (const float*)d_in[2];  const float* bqA = (const float*)d_in[3];
    const float* wkA = (const float*)d_in[4];  const float* bkA = (const float*)d_in[5];
    const float* wvA = (const float*)d_in[6];  const float* bvA = (const float*)d_in[7];
    const float* wpA = (const float*)d_in[8];  const float* bpA = (const float*)d_in[9];
    const float* wqB = (const float*)d_in[10]; const float* bqB = (const float*)d_in[11];
    const float* wkB = (const float*)d_in[12]; const float* bkB = (const float*)d_in[13];
    const float* wvB = (const float*)d_in[14]; const float* bvB = (const float*)d_in[15];
    const float* wpB = (const float*)d_in[16]; const float* bpB = (const float*)d_in[17];

    char* ws = (char*)d_ws;
    bf16_t* QtA  = (bf16_t*)(ws + 12877824);     // [B][N][128]
    bf16_t* KtA_ = (bf16_t*)(ws + 17072128);     // [B][N][128]
    bf16_t* VA_  = (bf16_t*)(ws + 21266432);     // [B][128][N]
    bf16_t* QtB  = (bf16_t*)(ws + 25460736);     // [B][N][64]
    bf16_t* KtB_ = (bf16_t*)(ws + 27557888);     // [B][N][64]
    bf16_t* VB_  = (bf16_t*)(ws + 29655040);     // [B][64][N]
    bf16_t* OtHA = (bf16_t*)(ws);                // [2][B][N][128] 8 MB
    float*  lHA  = (float*)(ws + 8388608);       // [2][16384] f32
    bf16_t* OtHB = (bf16_t*)(ws + 31752192);     // [2][B][N][64] 4 MB
    float*  lHB  = (float*)(ws + 35946496);      // [2][16384] f32

    k_prodf<<<512, 256, 49408, stream>>>(f2d, f3d,
        wqA, bqA, wkA, bkA, wvA, bvA, wqB, bqB, wkB, bkB, wvB, bvB,
        QtA, KtA_, VA_, QtB, KtB_, VB_);

    k_attn11<<<512, 256, 49152, stream>>>(QtA, KtA_, VA_, OtHA, lHA, QtB, KtB_, VB_, OtHB, lHB);

    k_outf<<<512, 256, 16384, stream>>>(OtHA, lHA, OtHB, lHB,
        wpA, bpA, f2d, wpB, bpB, f3d, (float*)d_out);
}

// Round 13
// 121.349 us; speedup vs baseline: 1.2623x; 1.2623x over previous
//
#include <hip/hip_runtime.h>
#include <hip/hip_bf16.h>
#include <math.h>

typedef __bf16 bf16_t;
typedef __bf16 bf16x8 __attribute__((ext_vector_type(8)));
typedef float f32x4 __attribute__((ext_vector_type(4)));
typedef float f32x16 __attribute__((ext_vector_type(16)));
typedef unsigned u32x2 __attribute__((ext_vector_type(2)));

#define NPOS 4096
#define LOG2E 1.4426950408889634f

__device__ __forceinline__ f32x4 mfma16(bf16x8 a, bf16x8 b, f32x4 c) {
    return __builtin_amdgcn_mfma_f32_16x16x32_bf16(a, b, c, 0, 0, 0);
}
__device__ __forceinline__ f32x16 mfma32(bf16x8 a, bf16x8 b, f32x16 c) {
    return __builtin_amdgcn_mfma_f32_32x32x16_bf16(a, b, c, 0, 0, 0);
}

typedef __attribute__((address_space(1))) const unsigned gas_u32;
typedef __attribute__((address_space(3))) unsigned las_u32;
__device__ __forceinline__ void gl_lds16(const char* g, char* l) {
    __builtin_amdgcn_global_load_lds((gas_u32*)g, (las_u32*)l, 16, 0, 0);
}

// raw v_exp_f32 (2^x)
__device__ __forceinline__ float fexp2(float x) {
    float r; asm("v_exp_f32 %0, %1" : "=v"(r) : "v"(x)); return r;
}

// counted-vmcnt barrier (T4)
#define BARC(N) do {                                                          \
    asm volatile("s_waitcnt vmcnt(" #N ") lgkmcnt(0)" ::: "memory");          \
    __builtin_amdgcn_sched_barrier(0);                                        \
    __builtin_amdgcn_s_barrier();                                             \
    __builtin_amdgcn_sched_barrier(0);                                        \
} while (0)

__device__ __forceinline__ char* sel3(char* a, char* b, char* c, int i) {
    return i == 0 ? a : (i == 1 ? b : c);
}

// ---- LDS tile layout (0-conflict, verified r4/r8/r9): 256B rows, byte ^= (row&15)<<4 ----
template<int BYTES>
__device__ __forceinline__ void stG(char* lds, const char* g, int w, int lane) {
    constexpr int NC = BYTES / 4096;
#pragma unroll
    for (int c = 0; c < NC; ++c) {
        int j = (w * NC + c) * 1024 + lane * 16;
        gl_lds16(g + (j ^ (((j >> 8) & 15) << 4)), lds + j);
    }
}
// 64-key V tile for D=64 (stream B): LDS row = 2 d-rows, col=(d&1)*128 + key*2
template<int BYTES>
__device__ __forceinline__ void stV(char* lds, const char* g, int w, int lane) {
    constexpr int NC = BYTES / 4096;
#pragma unroll
    for (int c = 0; c < NC; ++c) {
        int j = (w * NC + c) * 1024 + lane * 16;
        int row = j >> 8;
        int col = (j & 255) ^ ((row & 15) << 4);
        int d = (row << 1) | (col >> 7);
        gl_lds16(g + (size_t)d * (NPOS * 2) + (col & 127), lds + j);
    }
}
// 32-key V tile for D=128 (stream A): LDS row = 4 d-rows, col=(d&3)*64 + key*2
template<int BYTES>
__device__ __forceinline__ void stV32(char* lds, const char* g, int w, int lane) {
    constexpr int NC = BYTES / 4096;
#pragma unroll
    for (int c = 0; c < NC; ++c) {
        int j = (w * NC + c) * 1024 + lane * 16;
        int row = j >> 8;
        int col = (j & 255) ^ ((row & 15) << 4);
        int d = (row << 2) | (col >> 6);
        gl_lds16(g + (size_t)d * (NPOS * 2) + (col & 63), lds + j);
    }
}

template<int D>
__device__ __forceinline__ bf16x8 ldK(const char* lds, int key, int dbyte) {
    if constexpr (D == 128) {
        return *(const bf16x8*)(lds + key * 256 + (dbyte ^ ((key & 15) << 4)));
    } else {
        int row = key >> 1;
        int col = ((key & 1) << 7) | dbyte;
        return *(const bf16x8*)(lds + row * 256 + (col ^ ((row & 15) << 4)));
    }
}
__device__ __forceinline__ bf16x8 ldV(const char* lds, int d, int kbyte) {
    int row = d >> 1;
    int col = ((d & 1) << 7) | kbyte;
    return *(const bf16x8*)(lds + row * 256 + (col ^ ((row & 15) << 4)));
}
__device__ __forceinline__ bf16x8 ldV32(const char* lds, int d, int kbyte) {
    int row = d >> 2;
    int col = ((d & 3) << 6) | kbyte;
    return *(const bf16x8*)(lds + row * 256 + (col ^ ((row & 15) << 4)));
}

__device__ __forceinline__ unsigned pkbf(float a, float b) {
    union { bf16_t h[2]; unsigned u; } t;
    t.h[0] = (bf16_t)a; t.h[1] = (bf16_t)b;
    return t.u;
}
#define MKPA(sb, base) ({                                                   \
    unsigned a0_ = pkbf((sb)[(base)+0], (sb)[(base)+1]);                    \
    unsigned a1_ = pkbf((sb)[(base)+2], (sb)[(base)+3]);                    \
    unsigned a2_ = pkbf((sb)[(base)+4], (sb)[(base)+5]);                    \
    unsigned a3_ = pkbf((sb)[(base)+6], (sb)[(base)+7]);                    \
    u32x2 r0_ = __builtin_amdgcn_permlane32_swap(a2_, a0_, false, false);   \
    u32x2 r1_ = __builtin_amdgcn_permlane32_swap(a3_, a1_, false, false);   \
    union { unsigned u[4]; bf16x8 v; } pu_;                                 \
    pu_.u[0] = r0_.y; pu_.u[1] = r1_.y; pu_.u[2] = r0_.x; pu_.u[3] = r1_.x; \
    pu_.v; })

// ---------------- fused transpose (fp32->bf16) + weight convert (r11, proven) ----------------
__global__ __launch_bounds__(256) void k_trw(const float* __restrict__ s2d,
                                             const float* __restrict__ s3d,
                                             bf16_t* __restrict__ d2d,
                                             bf16_t* __restrict__ d3d,
                                             const float* w0, const float* w1, const float* w2, const float* w3,
                                             const float* w4, const float* w5, const float* w6, const float* w7,
                                             bf16_t* wdst)
{
    __shared__ float tile[64][65];
    int bid = blockIdx.x, tid = threadIdx.x;
    if (bid >= 1536) {
        int i = (bid - 1536) * 256 + tid;
        if      (i <  32768) wdst[i] = (bf16_t)w0[i];
        else if (i <  49152) wdst[i] = (bf16_t)w1[i - 32768];
        else if (i <  65536) wdst[i] = (bf16_t)w2[i - 49152];
        else if (i <  98304) wdst[i] = (bf16_t)w3[i - 65536];
        else if (i < 106496) wdst[i] = (bf16_t)w4[i - 98304];
        else if (i < 122880) wdst[i] = (bf16_t)w5[i - 106496];
        else if (i < 139264) wdst[i] = (bf16_t)w6[i - 122880];
        else if (i < 147456) wdst[i] = (bf16_t)w7[i - 139264];
        return;
    }
    const float* src; bf16_t* dst; int C, b, c0, n0;
    if (bid < 1024) { src = s2d; dst = d2d; C = 256; b = bid >> 8; c0 = ((bid >> 6) & 3) << 6; n0 = (bid & 63) << 6; }
    else { int r = bid - 1024; src = s3d; dst = d3d; C = 128; b = r >> 7; c0 = ((r >> 6) & 1) << 6; n0 = (r & 63) << 6; }
    const float* sp = src + ((size_t)b * C + c0) * NPOS + n0;
#pragma unroll
    for (int i = 0; i < 16; i++) {
        int idx = tid + i * 256; int c = idx >> 6, n = idx & 63;
        tile[c][n] = sp[(size_t)c * NPOS + n];
    }
    __syncthreads();
    bf16_t* dp = dst + ((size_t)b * NPOS + n0) * C + c0;
#pragma unroll
    for (int i = 0; i < 16; i++) {
        int idx = tid + i * 256; int n = idx >> 6, c = idx & 63;
        dp[(size_t)n * C + c] = (bf16_t)tile[c][n];
    }
}

// ------- producer body (r11, bf16 weights): from Xt[B][N][K] compute Q (scaled), K, V -------
template<int K, int MQ, int MK, int MV>
__device__ void prod_body(const bf16_t* __restrict__ Xt,
                          const bf16_t* __restrict__ wq, const float* __restrict__ bq, float sq,
                          const bf16_t* __restrict__ wk, const float* __restrict__ bk,
                          const bf16_t* __restrict__ wv, const float* __restrict__ bv,
                          bf16_t* __restrict__ Qo, bf16_t* __restrict__ Ko, bf16_t* __restrict__ Vo,
                          char* smem, int bid, int tid)
{
    constexpr int RB = K * 2;
    int b = bid >> 6, n0 = (bid & 63) << 6;
    int wave = tid >> 6, lane = tid & 63, g = lane >> 4, lr = lane & 15;

    const char* src = (const char*)(Xt + ((size_t)b * NPOS + n0) * K);
#pragma unroll
    for (int j0 = 0; j0 < 64 * RB; j0 += 4096) {
        int j = j0 + tid * 16;
        int row = j / RB;
        int col = j & (RB - 1);
        float4 v = *(const float4*)(src + (size_t)row * RB + col);
        *(float4*)(smem + row * RB + (col ^ ((row & 7) << 4))) = v;
    }
    __syncthreads();

    f32x4 aq[MQ / 16], ak[MK / 16], av[MV / 16];
#pragma unroll
    for (int ob = 0; ob < MQ / 16; ++ob) aq[ob] = f32x4{0.f,0.f,0.f,0.f};
#pragma unroll
    for (int ob = 0; ob < MK / 16; ++ob) ak[ob] = f32x4{0.f,0.f,0.f,0.f};
#pragma unroll
    for (int ob = 0; ob < MV / 16; ++ob) av[ob] = f32x4{0.f,0.f,0.f,0.f};
    int xrow = wave * 16 + lr;
#pragma unroll
    for (int ks = 0; ks < K / 32; ++ks) {
        bf16x8 xf = *(const bf16x8*)(smem + xrow * RB + ((((ks * 32 + g * 8) * 2)) ^ ((xrow & 7) << 4)));
#pragma unroll
        for (int ob = 0; ob < MQ / 16; ++ob) {
            bf16x8 wf = *(const bf16x8*)(wq + (size_t)(ob * 16 + lr) * K + ks * 32 + g * 8);
            aq[ob] = mfma16(xf, wf, aq[ob]);
        }
#pragma unroll
        for (int ob = 0; ob < MK / 16; ++ob) {
            bf16x8 wf = *(const bf16x8*)(wk + (size_t)(ob * 16 + lr) * K + ks * 32 + g * 8);
            ak[ob] = mfma16(xf, wf, ak[ob]);
        }
#pragma unroll
        for (int ob = 0; ob < MV / 16; ++ob) {
            bf16x8 wf = *(const bf16x8*)(wv + (size_t)(ob * 16 + lr) * K + ks * 32 + g * 8);
            av[ob] = mfma16(wf, xf, av[ob]);
        }
    }
#pragma unroll
    for (int ob = 0; ob < MQ / 16; ++ob) {
        int o = ob * 16 + lr;
        float bs = bq[o];
#pragma unroll
        for (int r = 0; r < 4; r++) {
            size_t n = (size_t)b * NPOS + n0 + wave * 16 + g * 4 + r;
            Qo[n * MQ + o] = (bf16_t)((aq[ob][r] + bs) * sq);
        }
    }
#pragma unroll
    for (int ob = 0; ob < MK / 16; ++ob) {
        int o = ob * 16 + lr;
        float bs = bk[o];
#pragma unroll
        for (int r = 0; r < 4; r++) {
            size_t n = (size_t)b * NPOS + n0 + wave * 16 + g * 4 + r;
            Ko[n * MK + o] = (bf16_t)(ak[ob][r] + bs);
        }
    }
#pragma unroll
    for (int ob = 0; ob < MV / 16; ++ob) {
#pragma unroll
        for (int r = 0; r < 4; r++) {
            int o = ob * 16 + g * 4 + r;
            size_t idx = ((size_t)b * MV + o) * NPOS + n0 + wave * 16 + lr;
            Vo[idx] = (bf16_t)(av[ob][r] + bv[o]);
        }
    }
}

// merged producer: 512 blocks, A-half and B-half in one launch
__global__ __launch_bounds__(256, 2) void k_prodm(const bf16_t* ft2d, const bf16_t* ft3d,
                                                  const bf16_t* wbf,
                                                  const float* bqA, const float* bkA, const float* bvA,
                                                  const float* bqB, const float* bkB, const float* bvB,
                                                  bf16_t* QtA, bf16_t* KtA_, bf16_t* VA_,
                                                  bf16_t* QtB, bf16_t* KtB_, bf16_t* VB_)
{
    extern __shared__ char smem[];
    const float sA = 0.08838834764831845f * LOG2E;
    const float sB = 0.125f * LOG2E;
    if (blockIdx.x < 256)
        prod_body<256, 128, 64, 64>(ft2d, wbf + 0, bqA, sA,
                                    wbf + 106496, bkB, wbf + 122880, bvB,
                                    QtA, KtB_, VB_, smem, blockIdx.x, threadIdx.x);
    else
        prod_body<128, 64, 128, 128>(ft3d, wbf + 98304, bqB, sB,
                                     wbf + 32768, bkA, wbf + 49152, bvA,
                                     QtB, KtA_, VA_, smem, blockIdx.x - 256, threadIdx.x);
}

// ---- output body (r11): 2-way l-merge + GEMM + bias + residual ----
template<int K, int M>
__device__ void out_body(const bf16_t* __restrict__ Xt,
                         const float* __restrict__ lp,
                         const bf16_t* __restrict__ W,
                         const float* __restrict__ bias,
                         const float* __restrict__ resid,
                         float* __restrict__ outp,
                         char* smem, int bid, int tid)
{
    constexpr int RB = K * 2;
    int b = bid >> 6, n0 = (bid & 63) << 6;
    int wave = tid >> 6, lane = tid & 63, g = lane >> 4, lr = lane & 15;

#pragma unroll
    for (int j0 = 0; j0 < 64 * RB; j0 += 4096) {
        int j = j0 + tid * 16;
        int row = j / RB;
        int colb = j & (RB - 1);
        size_t n = (size_t)b * NPOS + n0 + row;
        float l1 = lp[n], l2 = lp[16384 + n];
        float inv = 1.f / (l1 + l2);
        float w1 = l1 * inv, w2 = l2 * inv;
        bf16x8 o1 = *(const bf16x8*)(Xt + n * K + (colb >> 1));
        bf16x8 o2 = *(const bf16x8*)(Xt + (size_t)16384 * K + n * K + (colb >> 1));
        bf16x8 xv;
#pragma unroll
        for (int e = 0; e < 8; ++e) xv[e] = (bf16_t)(w1 * (float)o1[e] + w2 * (float)o2[e]);
        *(bf16x8*)(smem + row * RB + (colb ^ ((row & 7) << 4))) = xv;
    }
    __syncthreads();

    f32x4 acc[M / 16];
#pragma unroll
    for (int ob = 0; ob < M / 16; ++ob) acc[ob] = f32x4{0.f,0.f,0.f,0.f};
    int xrow = wave * 16 + lr;
#pragma unroll
    for (int ks = 0; ks < K / 32; ++ks) {
        bf16x8 xf = *(const bf16x8*)(smem + xrow * RB + ((((ks * 32 + g * 8) * 2)) ^ ((xrow & 7) << 4)));
#pragma unroll
        for (int ob = 0; ob < M / 16; ++ob) {
            bf16x8 wf = *(const bf16x8*)(W + (size_t)(ob * 16 + lr) * K + ks * 32 + g * 8);
            acc[ob] = mfma16(wf, xf, acc[ob]);
        }
    }
#pragma unroll
    for (int ob = 0; ob < M / 16; ++ob) {
#pragma unroll
        for (int r = 0; r < 4; r++) {
            int o = ob * 16 + g * 4 + r;
            size_t idx = ((size_t)b * M + o) * NPOS + n0 + wave * 16 + lr;
            outp[idx] = acc[ob][r] + bias[o] + resid[idx];
        }
    }
}

// merged output projection: 512 blocks
__global__ __launch_bounds__(256, 2) void k_outm(const bf16_t* OtHA, const float* lHA,
                                                 const bf16_t* OtHB, const float* lHB,
                                                 const bf16_t* wbf,
                                                 const float* bpA, const float* f2d,
                                                 const float* bpB, const float* f3d,
                                                 float* out)
{
    extern __shared__ char smem[];
    if (blockIdx.x < 256)
        out_body<128, 256>(OtHA, lHA, wbf + 65536, bpA, f2d, out, smem, blockIdx.x, threadIdx.x);
    else
        out_body<64, 128>(OtHB, lHB, wbf + 139264, bpB, f3d, out + 4194304, smem, blockIdx.x - 256, threadIdx.x);
}

// ======== attention A: D=128, KVBLK=32, K/V triple-buffered, software-pipelined (r11) ========
__device__ void attnA11(const bf16_t* __restrict__ Qt, const bf16_t* __restrict__ Kt,
                        const bf16_t* __restrict__ V, bf16_t* __restrict__ OtH,
                        float* __restrict__ lH, int b, int qblk, int half,
                        char* smem, int tid)
{
    char* Kb0 = smem;          char* Kb1 = smem + 8192;  char* Kb2 = smem + 16384;
    char* Vb0 = smem + 24576;  char* Vb1 = smem + 32768; char* Vb2 = smem + 40960;
    int w = tid >> 6, lane = tid & 63;
    int qcol = lane & 31, hi = lane >> 5;
    int q0 = qblk * 128 + w * 32;

    bf16x8 qf[8];
    const bf16_t* qp = Qt + ((size_t)b * NPOS + q0 + qcol) * 128 + hi * 8;
#pragma unroll
    for (int ks = 0; ks < 8; ++ks) qf[ks] = *(const bf16x8*)(qp + ks * 16);

    f32x16 acc[4];
#pragma unroll
    for (int cb = 0; cb < 4; ++cb)
#pragma unroll
        for (int i = 0; i < 16; ++i) acc[cb][i] = 0.f;
    float l_c = 0.f;

    const char* kg = (const char*)(Kt + (size_t)b * NPOS * 128) + (size_t)half * 64 * 8192;
    const char* vg = (const char*)(V + (size_t)b * 128 * NPOS) + (size_t)half * 4096;

    stG<8192>(Kb0, kg, w, lane);
    stV32<8192>(Vb0, vg, w, lane);
    stG<8192>(Kb1, kg + 8192, w, lane);
    stV32<8192>(Vb1, vg + 64, w, lane);
    BARC(4);

    f32x16 sE, sO;
#pragma unroll
    for (int i = 0; i < 16; ++i) sE[i] = 0.f;
#pragma unroll
    for (int ks = 0; ks < 8; ++ks)
        sE = mfma32(ldK<128>(Kb0, qcol, ks * 32 + hi * 16), qf[ks], sE);
    stG<8192>(Kb2, kg + 16384, w, lane);
    BARC(2);

    int ce = 0;
#pragma unroll 1
    for (int t2 = 0; t2 < 32; ++t2) {
        int t = 2 * t2;
        int c1 = ce + 1; if (c1 > 2) c1 -= 3;
        int c2 = ce + 2; if (c2 > 2) c2 -= 3;
        {
            int tK = t + 3; if (tK > 63) tK = 63;
            int tV = t + 2; if (tV > 63) tV = 63;
            stG<8192>(sel3(Kb0, Kb1, Kb2, ce), kg + (size_t)tK * 8192, w, lane);
            stV32<8192>(sel3(Vb0, Vb1, Vb2, c2), vg + (size_t)tV * 64, w, lane);
            const char* Kn = sel3(Kb0, Kb1, Kb2, c1);
#pragma unroll
            for (int i = 0; i < 16; ++i) sO[i] = 0.f;
            __builtin_amdgcn_s_setprio(1);
#pragma unroll
            for (int ks = 0; ks < 8; ++ks)
                sO = mfma32(ldK<128>(Kn, qcol, ks * 32 + hi * 16), qf[ks], sO);
            __builtin_amdgcn_s_setprio(0);
            float ps = 0.f;
#pragma unroll
            for (int i = 0; i < 16; ++i) { float e = fexp2(sE[i]); sE[i] = e; ps += e; }
            ps += __shfl_xor(ps, 32);
            l_c += ps;
            bf16x8 pa0 = MKPA(sE, 0), pa1 = MKPA(sE, 8);
            const char* Vc = sel3(Vb0, Vb1, Vb2, ce);
            __builtin_amdgcn_s_setprio(1);
#pragma unroll
            for (int cb = 0; cb < 4; ++cb) {
                int d = cb * 32 + qcol;
                acc[cb] = mfma32(pa0, ldV32(Vc, d, hi * 16), acc[cb]);
                acc[cb] = mfma32(pa1, ldV32(Vc, d, 32 + hi * 16), acc[cb]);
            }
            __builtin_amdgcn_s_setprio(0);
            BARC(4);
        }
        {
            int tK = t + 4; if (tK > 63) tK = 63;
            int tV = t + 3; if (tV > 63) tV = 63;
            stG<8192>(sel3(Kb0, Kb1, Kb2, c1), kg + (size_t)tK * 8192, w, lane);
            stV32<8192>(sel3(Vb0, Vb1, Vb2, ce), vg + (size_t)tV * 64, w, lane);
            const char* Kn = sel3(Kb0, Kb1, Kb2, c2);
#pragma unroll
            for (int i = 0; i < 16; ++i) sE[i] = 0.f;
            __builtin_amdgcn_s_setprio(1);
#pragma unroll
            for (int ks = 0; ks < 8; ++ks)
                sE = mfma32(ldK<128>(Kn, qcol, ks * 32 + hi * 16), qf[ks], sE);
            __builtin_amdgcn_s_setprio(0);
            float ps = 0.f;
#pragma unroll
            for (int i = 0; i < 16; ++i) { float e = fexp2(sO[i]); sO[i] = e; ps += e; }
            ps += __shfl_xor(ps, 32);
            l_c += ps;
            bf16x8 pa0 = MKPA(sO, 0), pa1 = MKPA(sO, 8);
            const char* Vc = sel3(Vb0, Vb1, Vb2, c1);
            __builtin_amdgcn_s_setprio(1);
#pragma unroll
            for (int cb = 0; cb < 4; ++cb) {
                int d = cb * 32 + qcol;
                acc[cb] = mfma32(pa0, ldV32(Vc, d, hi * 16), acc[cb]);
                acc[cb] = mfma32(pa1, ldV32(Vc, d, 32 + hi * 16), acc[cb]);
            }
            __builtin_amdgcn_s_setprio(0);
            BARC(4);
        }
        ce = c2;
    }

    float linv = 1.f / l_c;
    size_t obase = (size_t)(half * 4 + b) * NPOS;
#pragma unroll
    for (int r = 0; r < 16; ++r) {
        int crow = (r & 3) + 8 * (r >> 2) + 4 * hi;
        float lr = __shfl(linv, crow);
        size_t nrow = obase + q0 + crow;
#pragma unroll
        for (int cb = 0; cb < 4; ++cb)
            OtH[nrow * 128 + cb * 32 + qcol] = (bf16_t)(acc[cb][r] * lr);
    }
    if (lane < 32) lH[obase + q0 + lane] = l_c;
}

// ======== attention B: D=64, KVBLK=64, K/V triple-buffered, software-pipelined (r11) ========
__device__ void attnB11(const bf16_t* __restrict__ Qt, const bf16_t* __restrict__ Kt,
                        const bf16_t* __restrict__ V, bf16_t* __restrict__ OtH,
                        float* __restrict__ lH, int b, int qblk, int half,
                        char* smem, int tid)
{
    char* Kb0 = smem;          char* Kb1 = smem + 8192;  char* Kb2 = smem + 16384;
    char* Vb0 = smem + 24576;  char* Vb1 = smem + 32768; char* Vb2 = smem + 40960;
    int w = tid >> 6, lane = tid & 63;
    int qcol = lane & 31, hi = lane >> 5;
    int q0 = qblk * 128 + w * 32;

    bf16x8 qf[4];
    const bf16_t* qp = Qt + ((size_t)b * NPOS + q0 + qcol) * 64 + hi * 8;
#pragma unroll
    for (int ks = 0; ks < 4; ++ks) qf[ks] = *(const bf16x8*)(qp + ks * 16);

    f32x16 acc[2];
#pragma unroll
    for (int cb = 0; cb < 2; ++cb)
#pragma unroll
        for (int i = 0; i < 16; ++i) acc[cb][i] = 0.f;
    float l_c = 0.f;

    const char* kg = (const char*)(Kt + (size_t)b * NPOS * 64) + (size_t)half * 32 * 8192;
    const char* vg = (const char*)(V + (size_t)b * 64 * NPOS) + (size_t)half * 4096;

    stG<8192>(Kb0, kg, w, lane);
    stV<8192>(Vb0, vg, w, lane);
    stG<8192>(Kb1, kg + 8192, w, lane);
    stV<8192>(Vb1, vg + 128, w, lane);
    BARC(4);

    f32x16 sE0, sE1, sO0, sO1;
#pragma unroll
    for (int i = 0; i < 16; ++i) { sE0[i] = 0.f; sE1[i] = 0.f; }
#pragma unroll
    for (int ks = 0; ks < 4; ++ks) {
        int dbyte = ks * 32 + hi * 16;
        sE0 = mfma32(ldK<64>(Kb0, qcol, dbyte), qf[ks], sE0);
        sE1 = mfma32(ldK<64>(Kb0, 32 + qcol, dbyte), qf[ks], sE1);
    }
    stG<8192>(Kb2, kg + 16384, w, lane);
    BARC(2);

    int ce = 0;
#pragma unroll 1
    for (int t2 = 0; t2 < 16; ++t2) {
        int t = 2 * t2;
        int c1 = ce + 1; if (c1 > 2) c1 -= 3;
        int c2 = ce + 2; if (c2 > 2) c2 -= 3;
        {
            int tK = t + 3; if (tK > 31) tK = 31;
            int tV = t + 2; if (tV > 31) tV = 31;
            stG<8192>(sel3(Kb0, Kb1, Kb2, ce), kg + (size_t)tK * 8192, w, lane);
            stV<8192>(sel3(Vb0, Vb1, Vb2, c2), vg + (size_t)tV * 128, w, lane);
            const char* Kn = sel3(Kb0, Kb1, Kb2, c1);
#pragma unroll
            for (int i = 0; i < 16; ++i) { sO0[i] = 0.f; sO1[i] = 0.f; }
            __builtin_amdgcn_s_setprio(1);
#pragma unroll
            for (int ks = 0; ks < 4; ++ks) {
                int dbyte = ks * 32 + hi * 16;
                sO0 = mfma32(ldK<64>(Kn, qcol, dbyte), qf[ks], sO0);
                sO1 = mfma32(ldK<64>(Kn, 32 + qcol, dbyte), qf[ks], sO1);
            }
            __builtin_amdgcn_s_setprio(0);
            float ps = 0.f;
#pragma unroll
            for (int i = 0; i < 16; ++i) { float e = fexp2(sE0[i]); sE0[i] = e; ps += e; }
#pragma unroll
            for (int i = 0; i < 16; ++i) { float e = fexp2(sE1[i]); sE1[i] = e; ps += e; }
            ps += __shfl_xor(ps, 32);
            l_c += ps;
            bf16x8 pa0 = MKPA(sE0, 0), pa1 = MKPA(sE0, 8);
            bf16x8 pa2 = MKPA(sE1, 0), pa3 = MKPA(sE1, 8);
            const char* Vc = sel3(Vb0, Vb1, Vb2, ce);
            __builtin_amdgcn_s_setprio(1);
#pragma unroll
            for (int cb = 0; cb < 2; ++cb) {
                int d = cb * 32 + qcol;
                acc[cb] = mfma32(pa0, ldV(Vc, d, 0  + hi * 16), acc[cb]);
                acc[cb] = mfma32(pa1, ldV(Vc, d, 32 + hi * 16), acc[cb]);
                acc[cb] = mfma32(pa2, ldV(Vc, d, 64 + hi * 16), acc[cb]);
                acc[cb] = mfma32(pa3, ldV(Vc, d, 96 + hi * 16), acc[cb]);
            }
            __builtin_amdgcn_s_setprio(0);
            BARC(4);
        }
        {
            int tK = t + 4; if (tK > 31) tK = 31;
            int tV = t + 3; if (tV > 31) tV = 31;
            stG<8192>(sel3(Kb0, Kb1, Kb2, c1), kg + (size_t)tK * 8192, w, lane);
            stV<8192>(sel3(Vb0, Vb1, Vb2, ce), vg + (size_t)tV * 128, w, lane);
            const char* Kn = sel3(Kb0, Kb1, Kb2, c2);
#pragma unroll
            for (int i = 0; i < 16; ++i) { sE0[i] = 0.f; sE1[i] = 0.f; }
            __builtin_amdgcn_s_setprio(1);
#pragma unroll
            for (int ks = 0; ks < 4; ++ks) {
                int dbyte = ks * 32 + hi * 16;
                sE0 = mfma32(ldK<64>(Kn, qcol, dbyte), qf[ks], sE0);
                sE1 = mfma32(ldK<64>(Kn, 32 + qcol, dbyte), qf[ks], sE1);
            }
            __builtin_amdgcn_s_setprio(0);
            float ps = 0.f;
#pragma unroll
            for (int i = 0; i < 16; ++i) { float e = fexp2(sO0[i]); sO0[i] = e; ps += e; }
#pragma unroll
            for (int i = 0; i < 16; ++i) { float e = fexp2(sO1[i]); sO1[i] = e; ps += e; }
            ps += __shfl_xor(ps, 32);
            l_c += ps;
            bf16x8 pa0 = MKPA(sO0, 0), pa1 = MKPA(sO0, 8);
            bf16x8 pa2 = MKPA(sO1, 0), pa3 = MKPA(sO1, 8);
            const char* Vc = sel3(Vb0, Vb1, Vb2, c1);
            __builtin_amdgcn_s_setprio(1);
#pragma unroll
            for (int cb = 0; cb < 2; ++cb) {
                int d = cb * 32 + qcol;
                acc[cb] = mfma32(pa0, ldV(Vc, d, 0  + hi * 16), acc[cb]);
                acc[cb] = mfma32(pa1, ldV(Vc, d, 32 + hi * 16), acc[cb]);
                acc[cb] = mfma32(pa2, ldV(Vc, d, 64 + hi * 16), acc[cb]);
                acc[cb] = mfma32(pa3, ldV(Vc, d, 96 + hi * 16), acc[cb]);
            }
            __builtin_amdgcn_s_setprio(0);
            BARC(4);
        }
        ce = c2;
    }

    float linv = 1.f / l_c;
    size_t obase = (size_t)(half * 4 + b) * NPOS;
#pragma unroll
    for (int r = 0; r < 16; ++r) {
        int crow = (r & 3) + 8 * (r >> 2) + 4 * hi;
        float lr = __shfl(linv, crow);
        size_t nrow = obase + q0 + crow;
#pragma unroll
        for (int cb = 0; cb < 2; ++cb)
            OtH[nrow * 64 + cb * 32 + qcol] = (bf16_t)(acc[cb][r] * lr);
    }
    if (lane < 32) lH[obase + q0 + lane] = l_c;
}

__global__ __launch_bounds__(256, 2) void k_attn11(const bf16_t* QtA, const bf16_t* KtA, const bf16_t* VA,
                                                   bf16_t* OtHA, float* lHA,
                                                   const bf16_t* QtB, const bf16_t* KtB, const bf16_t* VB,
                                                   bf16_t* OtHB, float* lHB)
{
    extern __shared__ char smem[];
    int bid = blockIdx.x, tid = threadIdx.x;
    if (bid < 256) {
        int x = bid & 7;   // XCD = (b<<1)|half keeps K/V half in its L2
        attnA11(QtA, KtA, VA, OtHA, lHA, x >> 1, bid >> 3, x & 1, smem, tid);
    } else {
        int u = bid - 256;
        int x = u & 7;
        attnB11(QtB, KtB, VB, OtHB, lHB, x >> 1, u >> 3, x & 1, smem, tid);
    }
}

extern "C" void kernel_launch(void* const* d_in, const int* in_sizes, int n_in,
                              void* d_out, int out_size, void* d_ws, size_t ws_size,
                              hipStream_t stream)
{
    (void)in_sizes; (void)n_in; (void)out_size; (void)ws_size;
    const float* f2d = (const float*)d_in[0];
    const float* f3d = (const float*)d_in[1];
    const float* wqA = (const float*)d_in[2];  const float* bqA = (const float*)d_in[3];
    const float* wkA = (const float*)d_in[4];  const float* bkA = (const float*)d_in[5];
    const float* wvA = (const float*)d_in[6];  const float* bvA = (const float*)d_in[7];
    const float* wpA = (const float*)d_in[8];  const float* bpA = (const float*)d_in[9];
    const float* wqB = (const float*)d_in[10]; const float* bqB = (const float*)d_in[11];
    const float* wkB = (const float*)d_in[12]; const float* bkB = (const float*)d_in[13];
    const float* wvB = (const float*)d_in[14]; const float* bvB = (const float*)d_in[15];
    const float* wpB = (const float*)d_in[16]; const float* bpB = (const float*)d_in[17];

    char* ws = (char*)d_ws;
    bf16_t* ft2d = (bf16_t*)(ws);                // 8 MB (dead after producers)
    bf16_t* ft3d = (bf16_t*)(ws + 8388608);      // 4 MB (dead after producers)
    bf16_t* wbf  = (bf16_t*)(ws + 12582912);     // 294912 B
    bf16_t* QtA  = (bf16_t*)(ws + 12877824);     // [B][N][128]
    bf16_t* KtA_ = (bf16_t*)(ws + 17072128);     // [B][N][128]
    bf16_t* VA_  = (bf16_t*)(ws + 21266432);     // [B][128][N]
    bf16_t* QtB  = (bf16_t*)(ws + 25460736);     // [B][N][64]
    bf16_t* KtB_ = (bf16_t*)(ws + 27557888);     // [B][N][64]
    bf16_t* VB_  = (bf16_t*)(ws + 29655040);     // [B][64][N]
    bf16_t* OtHA = (bf16_t*)(ws);                // [2][B][N][128] 8 MB (over dead ft2d)
    float*  lHA  = (float*)(ws + 8388608);       // [2][16384] f32 (over dead ft3d)
    bf16_t* OtHB = (bf16_t*)(ws + 31752192);     // [2][B][N][64] 4 MB
    float*  lHB  = (float*)(ws + 35946496);      // [2][16384] f32

    k_trw<<<2112, 256, 0, stream>>>(f2d, f3d, ft2d, ft3d,
                                    wqA, wkA, wvA, wpA, wqB, wkB, wvB, wpB, wbf);

    k_prodm<<<512, 256, 32768, stream>>>(ft2d, ft3d, wbf,
        bqA, bkA, bvA, bqB, bkB, bvB,
        QtA, KtA_, VA_, QtB, KtB_, VB_);

    k_attn11<<<512, 256, 49152, stream>>>(QtA, KtA_, VA_, OtHA, lHA, QtB, KtB_, VB_, OtHB, lHB);

    k_outm<<<512, 256, 16384, stream>>>(OtHA, lHA, OtHB, lHB, wbf,
        bpA, f2d, bpB, f3d, (float*)d_out);
}